// Round 3
// baseline (14146.677 us; speedup 1.0000x reference)
//
#include <hip/hip_runtime.h>
#include <hip/hip_bf16.h>
#include <cstddef>

typedef __bf16 bf16_t;
typedef bf16_t bf16x8 __attribute__((ext_vector_type(8)));
typedef bf16_t bf16x4 __attribute__((ext_vector_type(4)));
typedef float  f32x4  __attribute__((ext_vector_type(4)));

#define T_STEPS 256
#define BATCH   32
#define HDIM    1024
#define ZDIM    4096

// ---------------- sizes ----------------
constexpr size_t SZ_H0    = (size_t)8192 * 1024 * 4;      // fp32 h0seq, 32 MiB
constexpr size_t SZ_RING  = (size_t)2 * 32 * 1024 * 4;    // 256 KiB
constexpr size_t SZ_STATS = (size_t)256 * 4 * 8 * 2 * 4;  // 64 KiB per layer
constexpr size_t SZ_CTR   = (size_t)2 * 256 * 4 * 4;      // 8 KiB per layer (s+h)
constexpr size_t SZ_CST   = (size_t)32 * 1024 * 4;        // 128 KiB c-state
constexpr size_t SZ_MU    = 256;                          // mu-state (padded)
constexpr size_t SZ_TAIL  = 2*SZ_RING + 2*SZ_STATS + 2*SZ_CTR + SZ_CST + SZ_MU;
constexpr int    ZERO_WORDS = (int)((2*SZ_STATS + 2*SZ_CTR) / 4);

// scan LDS: staging slabs (hi+lo, 64 rows x 264 k) alias the per-step h area
constexpr int SLAB_STRIDE = 264;                       // 528 B row = 33 x 16 B (b128-aligned)
constexpr int HL_STRIDE   = 1040;                      // 2080 B row = 130 x 16 B
constexpr int SCAN_LDS    = 2 * 64 * SLAB_STRIDE * 2;  // 67584 > h area (33280+512)

__global__ void init_zero(unsigned* __restrict__ p, int n) {
    int i = blockIdx.x * blockDim.x + threadIdx.x;
    if (i < n) p[i] = 0u;
}

__device__ __forceinline__ void split_bf16(float v, bf16_t& hi, bf16_t& lo) {
    hi = (bf16_t)v;
    lo = (bf16_t)(v - (float)hi);
}

// ---------------- input-projection GEMM (split-precision bf16x2) ----------------
// xp[r_loc][n] = sum_k A[r_glob][k]*W[k][n] + bias[n], fp32-accurate via 3-term MFMA.
// ROWMAP (layer0): r_glob -> series[b][t][0:256], K=256.  else (layer1): A row r_glob, K=1024.
template<int KTOT, bool ROWMAP>
__global__ __launch_bounds__(256) void gemm_xp(
    const float* __restrict__ A,
    const float* __restrict__ W,
    const float* __restrict__ bias,
    float*       __restrict__ xp,
    int t0)
{
    __shared__ bf16_t Ash[64][40], Asl[64][40], Bsh[64][40], Bsl[64][40];
    const int bm = blockIdx.x / (ZDIM/64);
    const int bn = blockIdx.x % (ZDIM/64);
    const int tid  = threadIdx.x;
    const int lane = tid & 63;
    const int w    = tid >> 6;
    const int wm = w >> 1, wn = w & 1;
    const int q   = lane >> 4;
    const int l15 = lane & 15;

    f32x4 acc[2][2] = {};

    const int sm = tid & 63;
    const int sk = (tid >> 6) * 8;
    const int gr_glob = t0*32 + bm*64 + sm;
    const float* Arow;
    if constexpr (ROWMAP) {
        int tt = gr_glob >> 5, bb = gr_glob & 31;
        Arow = A + ((size_t)bb * T_STEPS + tt) * 256;
    } else {
        Arow = A + (size_t)gr_glob * HDIM;
    }
    const int gcol = bn*64 + sm;

    for (int k0 = 0; k0 < KTOT; k0 += 32) {
        {
            f32x4 a0 = *(const f32x4*)(Arow + k0 + sk);
            f32x4 a1 = *(const f32x4*)(Arow + k0 + sk + 4);
            #pragma unroll
            for (int j = 0; j < 4; ++j) {
                split_bf16(a0[j], Ash[sm][sk+j],   Asl[sm][sk+j]);
                split_bf16(a1[j], Ash[sm][sk+4+j], Asl[sm][sk+4+j]);
            }
        }
        #pragma unroll
        for (int j = 0; j < 8; ++j) {
            float wv = W[(size_t)(k0 + sk + j) * ZDIM + gcol];
            split_bf16(wv, Bsh[sm][sk+j], Bsl[sm][sk+j]);
        }
        __syncthreads();
        #pragma unroll
        for (int mt = 0; mt < 2; ++mt) {
            #pragma unroll
            for (int nt = 0; nt < 2; ++nt) {
                bf16x8 ah = *(const bf16x8*)&Ash[wm*32 + mt*16 + l15][q*8];
                bf16x8 al = *(const bf16x8*)&Asl[wm*32 + mt*16 + l15][q*8];
                bf16x8 bh = *(const bf16x8*)&Bsh[wn*32 + nt*16 + l15][q*8];
                bf16x8 bl = *(const bf16x8*)&Bsl[wn*32 + nt*16 + l15][q*8];
                acc[mt][nt] = __builtin_amdgcn_mfma_f32_16x16x32_bf16(ah, bh, acc[mt][nt], 0, 0, 0);
                acc[mt][nt] = __builtin_amdgcn_mfma_f32_16x16x32_bf16(al, bh, acc[mt][nt], 0, 0, 0);
                acc[mt][nt] = __builtin_amdgcn_mfma_f32_16x16x32_bf16(ah, bl, acc[mt][nt], 0, 0, 0);
            }
        }
        __syncthreads();
    }
    #pragma unroll
    for (int mt = 0; mt < 2; ++mt) {
        int row = bm*64 + wm*32 + mt*16 + q*4;
        #pragma unroll
        for (int nt = 0; nt < 2; ++nt) {
            int col = bn*64 + wn*32 + nt*16 + l15;
            float bia = bias[col];
            #pragma unroll
            for (int r = 0; r < 4; ++r)
                xp[(size_t)(row + r)*ZDIM + col] = acc[mt][nt][r] + bia;
        }
    }
}

// ---------------- persistent recurrent scan (split-precision, chunked) ----------------
// grid = 256 x 256. group gid = blk>>6 owns batches 8*gid..+7; block lid = blk&63 owns
// h-cols H0=lid*16..+15. Recurrent W held in REGISTERS as hi/lo bf16 A-fragments
// (rr = hc*4+gate; wave w rows 16w..16w+15; ~256 VGPRs -> 1 wave/SIMD, fine: latency-bound).
// MFMA C map: n=lane&15=batch, m=4q+reg -> reg=gate, hcl=4w+q. Lane-local cell update.
// Chunk [t0,t1): c/mu state in global between launches; hring/ctr/stats persist.
__global__ __launch_bounds__(256, 1) void scan_kernel(
    const float* __restrict__ Wh,     // [1024][4096] fp32 recurrent rows
    const float* __restrict__ xp,     // [cT*32][4096] fp32 chunk x-proj (incl bias)
    const float* __restrict__ gamma,
    const float* __restrict__ beta,
    float*       __restrict__ hring,  // [2][32][1024] fp32
    float*       __restrict__ hseq,   // [T*32][1024] fp32 or null (layer0)
    float*       __restrict__ outlast,// [32][1024] fp32 or null (layer1)
    float*       __restrict__ stats,  // [T][4][8][2] fp32 (zeroed)
    unsigned*    __restrict__ ctr_s,  // [T][4]
    unsigned*    __restrict__ ctr_h,  // [T][4]
    float*       __restrict__ cstate, // [32][1024] fp32
    float*       __restrict__ mustate,// [32] fp32
    int t0, int t1)
{
    extern __shared__ char smem[];
    bf16_t* slab_hi = (bf16_t*)smem;                         // [64][264]
    bf16_t* slab_lo = (bf16_t*)(smem + 64*SLAB_STRIDE*2);
    bf16_t* hl_hi   = (bf16_t*)smem;                         // aliases slabs after staging
    bf16_t* hl_lo   = (bf16_t*)(smem + 8*HL_STRIDE*2);
    float*  sred    = (float*) (smem + 16*HL_STRIDE*2);      // [4][16][2]

    const int gid = blockIdx.x >> 6;
    const int lid = blockIdx.x & 63;
    const int B0  = gid * 8;
    const int H0  = lid * 16;
    const int tid  = threadIdx.x;
    const int lane = tid & 63;
    const int w    = tid >> 6;
    const int q    = lane >> 4;
    const int l15  = lane & 15;

    // ---- stage recurrent W slice -> registers (hi/lo A-fragments), via LDS slabs ----
    bf16x8 wf_hi[32], wf_lo[32];
    {
        const int kw   = tid >> 6;        // 0..3
        const int strip= (tid >> 4) & 3;  // gate
        const int col  = tid & 15;        // hc
        const int gc2  = strip*1024 + H0 + col;
        const int rr_w = col*4 + strip;
        #pragma unroll
        for (int s = 0; s < 4; ++s) {
            for (int j = 0; j < 64; ++j) {
                int kk = j*4 + kw;
                float v = Wh[(size_t)(s*256 + kk)*ZDIM + gc2];
                bf16_t hi, lo; split_bf16(v, hi, lo);
                slab_hi[rr_w*SLAB_STRIDE + kk] = hi;
                slab_lo[rr_w*SLAB_STRIDE + kk] = lo;
            }
            __syncthreads();
            #pragma unroll
            for (int kbl = 0; kbl < 8; ++kbl) {
                wf_hi[s*8+kbl] = *(const bf16x8*)&slab_hi[(16*w + l15)*SLAB_STRIDE + kbl*32 + q*8];
                wf_lo[s*8+kbl] = *(const bf16x8*)&slab_lo[(16*w + l15)*SLAB_STRIDE + kbl*32 + q*8];
            }
            __syncthreads();
        }
    }

    const int  bidx  = l15;
    const bool valid = bidx < 8;
    const int  batch = B0 + bidx;
    const int  hcl   = 4*w + q;
    const int  hcg   = H0 + hcl;
    const float g_r = gamma[hcg];
    const float b_r = beta[hcg];
    const size_t xpbase = (size_t)batch * ZDIM + (size_t)H0 + hcl;
    const int hrow = (l15 < 8) ? l15 : 7;

    float c = 0.f, mu_prev = 0.f;
    if (t0 > 0 && valid) {
        c = cstate[(size_t)batch*HDIM + hcg];
        mu_prev = mustate[batch];
    }

    #pragma unroll 1
    for (int t = t0; t < t1; ++t) {
        float xpv[4];
        {
            const float* xpt = xp + (size_t)(t - t0) * (BATCH*ZDIM) + xpbase;
            #pragma unroll
            for (int r = 0; r < 4; ++r) xpv[r] = valid ? xpt[(size_t)r * 1024] : 0.f;
        }
        f32x4 acc_hh = {0.f,0.f,0.f,0.f}, acc_lh = acc_hh, acc_hl = acc_hh;
        if (t > 0) {
            if (tid == 0) {
                while (__hip_atomic_load(&ctr_h[(t-1)*4 + gid], __ATOMIC_RELAXED,
                                         __HIP_MEMORY_SCOPE_AGENT) < 64u)
                    __builtin_amdgcn_s_sleep(1);
                (void)__hip_atomic_load(&ctr_h[(t-1)*4 + gid], __ATOMIC_ACQUIRE,
                                        __HIP_MEMORY_SCOPE_AGENT);
            }
            __syncthreads();
            {   // stage h (fp32 -> hi/lo bf16) into LDS
                int row = tid >> 5;
                int li  = tid & 31;
                const float* hr = hring + (((size_t)((t-1)&1) * 32) + B0 + row) * HDIM;
                #pragma unroll
                for (int j = 0; j < 8; ++j) {
                    f32x4 v = ((const f32x4*)hr)[li + j*32];
                    bf16x4 bh, bl;
                    #pragma unroll
                    for (int e = 0; e < 4; ++e) { bf16_t hi, lo; split_bf16(v[e], hi, lo); bh[e]=hi; bl[e]=lo; }
                    *(bf16x4*)&hl_hi[row*HL_STRIDE + (li + j*32)*4] = bh;
                    *(bf16x4*)&hl_lo[row*HL_STRIDE + (li + j*32)*4] = bl;
                }
            }
            __syncthreads();
            const bf16_t* Bh = hl_hi + (size_t)hrow * HL_STRIDE + q*8;
            const bf16_t* Bl = hl_lo + (size_t)hrow * HL_STRIDE + q*8;
            #pragma unroll
            for (int kb = 0; kb < 32; ++kb) {
                bf16x8 bh = *(const bf16x8*)(Bh + kb*32);
                bf16x8 bl = *(const bf16x8*)(Bl + kb*32);
                acc_hh = __builtin_amdgcn_mfma_f32_16x16x32_bf16(wf_hi[kb], bh, acc_hh, 0, 0, 0);
                acc_lh = __builtin_amdgcn_mfma_f32_16x16x32_bf16(wf_lo[kb], bh, acc_lh, 0, 0, 0);
                acc_hl = __builtin_amdgcn_mfma_f32_16x16x32_bf16(wf_hi[kb], bl, acc_hl, 0, 0, 0);
            }
        }
        float z[4];
        #pragma unroll
        for (int r = 0; r < 4; ++r)
            z[r] = ((acc_lh[r] + acc_hl[r]) + acc_hh[r]) + xpv[r];
        float zi = fminf(fmaxf(z[0], -6.f), 3.f);
        float zf = fminf(fmaxf(z[1], -6.f), 3.f);
        float ig = __expf(zi);
        float fg = __expf(zf);
        float cand = tanhf(z[2]);
        float sg = 1.f / (1.f + __expf(-z[3]));
        c = fg * c + ig * cand;

        // LN stats (shifted by mu_prev against cancellation)
        float dm = valid ? (c - mu_prev) : 0.f;
        float s1 = dm, s2 = dm * dm;
        s1 += __shfl_xor(s1, 16); s2 += __shfl_xor(s2, 16);
        s1 += __shfl_xor(s1, 32); s2 += __shfl_xor(s2, 32);
        if (q == 0) { sred[(w*16 + l15)*2] = s1; sred[(w*16 + l15)*2 + 1] = s2; }
        __syncthreads();
        if (w == 0 && q == 0 && l15 < 8) {
            float S1 = 0.f, S2 = 0.f;
            #pragma unroll
            for (int ww = 0; ww < 4; ++ww) {
                S1 += sred[(ww*16 + l15)*2];
                S2 += sred[(ww*16 + l15)*2 + 1];
            }
            float* sp = stats + ((size_t)t*4 + gid)*16 + l15*2;
            __hip_atomic_fetch_add(sp,     S1, __ATOMIC_RELAXED, __HIP_MEMORY_SCOPE_AGENT);
            __hip_atomic_fetch_add(sp + 1, S2, __ATOMIC_RELAXED, __HIP_MEMORY_SCOPE_AGENT);
        }
        if (tid == 0) {
            __hip_atomic_fetch_add(&ctr_s[t*4 + gid], 1u, __ATOMIC_RELEASE,
                                   __HIP_MEMORY_SCOPE_AGENT);
            while (__hip_atomic_load(&ctr_s[t*4 + gid], __ATOMIC_RELAXED,
                                     __HIP_MEMORY_SCOPE_AGENT) < 64u)
                __builtin_amdgcn_s_sleep(1);
            (void)__hip_atomic_load(&ctr_s[t*4 + gid], __ATOMIC_ACQUIRE,
                                    __HIP_MEMORY_SCOPE_AGENT);
        }
        __syncthreads();
        if (valid) {
            const float* sp = stats + ((size_t)t*4 + gid)*16 + bidx*2;
            float S1 = __hip_atomic_load(sp,     __ATOMIC_RELAXED, __HIP_MEMORY_SCOPE_AGENT);
            float S2 = __hip_atomic_load(sp + 1, __ATOMIC_RELAXED, __HIP_MEMORY_SCOPE_AGENT);
            float dmu = S1 * (1.f/1024.f);
            float mu  = mu_prev + dmu;
            float var = S2 * (1.f/1024.f) - dmu*dmu;
            float ln  = (c - mu) * rsqrtf(var + 1e-5f) * g_r + b_r;
            float hv  = sg * tanhf(ln);
            mu_prev = mu;
            __hip_atomic_store(&hring[((size_t)(t&1)*32 + batch)*HDIM + hcg], hv,
                               __ATOMIC_RELAXED, __HIP_MEMORY_SCOPE_AGENT);
            if (hseq)    hseq[((size_t)t*32 + batch)*HDIM + hcg] = hv;
            if (outlast && t == T_STEPS-1) outlast[(size_t)batch*HDIM + hcg] = hv;
        }
        __syncthreads();  // drains vmcnt: h stores complete before counter bump
        if (tid == 0)
            __hip_atomic_fetch_add(&ctr_h[t*4 + gid], 1u, __ATOMIC_RELEASE,
                                   __HIP_MEMORY_SCOPE_AGENT);
    }

    if (t1 < T_STEPS) {
        if (valid) cstate[(size_t)batch*HDIM + hcg] = c;
        if (lid == 0 && w == 0 && q == 0 && l15 < 8) mustate[B0 + l15] = mu_prev;
    }
}

extern "C" void kernel_launch(void* const* d_in, const int* in_sizes, int n_in,
                              void* d_out, int out_size, void* d_ws, size_t ws_size,
                              hipStream_t stream) {
    (void)in_sizes; (void)n_in;
    const float* series = (const float*)d_in[0];
    const float* W0  = (const float*)d_in[1];
    const float* b0  = (const float*)d_in[2];
    const float* g0  = (const float*)d_in[3];
    const float* be0 = (const float*)d_in[4];
    const float* W1  = (const float*)d_in[5];
    const float* b1  = (const float*)d_in[6];
    const float* g1  = (const float*)d_in[7];
    const float* be1 = (const float*)d_in[8];
    float* out = (float*)d_out;
    unsigned char* ws = (unsigned char*)d_ws;

    // pick the largest time-chunk whose fp32 xp buffer fits the workspace
    int cT = 0;
    const int cands[5] = {256, 128, 64, 32, 16};
    for (int i = 0; i < 5; ++i) {
        size_t need = (size_t)cands[i]*32*ZDIM*4 + SZ_H0 + SZ_TAIL;
        if (need <= ws_size) { cT = cands[i]; break; }
    }
    if (cT == 0) {  // cannot run without faulting
        (void)hipMemsetAsync(d_out, 0, (size_t)out_size * sizeof(float), stream);
        return;
    }
    const size_t sz_xp = (size_t)cT*32*ZDIM*4;
    float*    xp     = (float*)   (ws);
    float*    h0seq  = (float*)   (ws + sz_xp);
    float*    hring0 = (float*)   (ws + sz_xp + SZ_H0);
    float*    hring1 = (float*)   (ws + sz_xp + SZ_H0 + SZ_RING);
    float*    stats0 = (float*)   (ws + sz_xp + SZ_H0 + 2*SZ_RING);
    float*    stats1 = (float*)   (ws + sz_xp + SZ_H0 + 2*SZ_RING + SZ_STATS);
    unsigned* ctr0   = (unsigned*)(ws + sz_xp + SZ_H0 + 2*SZ_RING + 2*SZ_STATS);
    unsigned* ctr1   = (unsigned*)(ws + sz_xp + SZ_H0 + 2*SZ_RING + 2*SZ_STATS + SZ_CTR);
    float*    cstate = (float*)   (ws + sz_xp + SZ_H0 + 2*SZ_RING + 2*SZ_STATS + 2*SZ_CTR);
    float*    mustate= (float*)   (ws + sz_xp + SZ_H0 + 2*SZ_RING + 2*SZ_STATS + 2*SZ_CTR + SZ_CST);

    (void)hipFuncSetAttribute((const void*)scan_kernel,
                              hipFuncAttributeMaxDynamicSharedMemorySize, SCAN_LDS);

    init_zero<<<(ZERO_WORDS + 255)/256, 256, 0, stream>>>((unsigned*)stats0, ZERO_WORDS);

    const int nch = T_STEPS / cT;
    const int gemm_grid = (cT*32/64) * (ZDIM/64);

    // ---- layer 0 ----
    for (int ci = 0; ci < nch; ++ci) {
        int t0 = ci*cT, t1 = t0 + cT;
        gemm_xp<256, true><<<gemm_grid, 256, 0, stream>>>(series, W0, b0, xp, t0);
        scan_kernel<<<256, 256, SCAN_LDS, stream>>>(
            W0 + (size_t)256*ZDIM, xp, g0, be0, hring0, h0seq, nullptr,
            stats0, ctr0, ctr0 + T_STEPS*4, cstate, mustate, t0, t1);
    }
    // ---- layer 1 ----
    for (int ci = 0; ci < nch; ++ci) {
        int t0 = ci*cT, t1 = t0 + cT;
        gemm_xp<1024, false><<<gemm_grid, 256, 0, stream>>>(h0seq, W1, b1, xp, t0);
        scan_kernel<<<256, 256, SCAN_LDS, stream>>>(
            W1 + (size_t)1024*ZDIM, xp, g1, be1, hring1, nullptr, out,
            stats1, ctr1, ctr1 + T_STEPS*4, cstate, mustate, t0, t1);
    }
}

// Round 4
// 11139.422 us; speedup vs baseline: 1.2700x; 1.2700x over previous
//
#include <hip/hip_runtime.h>
#include <hip/hip_bf16.h>
#include <cstddef>

typedef __bf16 bf16_t;
typedef bf16_t bf16x8 __attribute__((ext_vector_type(8)));
typedef bf16_t bf16x4 __attribute__((ext_vector_type(4)));
typedef float  f32x4  __attribute__((ext_vector_type(4)));

#define T_STEPS 256
#define BATCH   32
#define HDIM    1024
#define ZDIM    4096

// ---------------- sizes ----------------
constexpr size_t SZ_H0    = (size_t)8192 * 1024 * 4;      // fp32 h0seq, 32 MiB
constexpr size_t SZ_RING  = (size_t)2 * 32 * 1024 * 4;    // 256 KiB
constexpr size_t SZ_SPART = (size_t)256 * 4 * 64 * 16 * 4; // 16 MiB stats partials (shared)
constexpr size_t SZ_FLAG  = (size_t)256 * 4 * 64 * 4;      // 256 KiB per flag array
constexpr size_t SZ_CST   = (size_t)32 * 1024 * 4;         // 128 KiB c-state
constexpr size_t SZ_MU    = 256;
constexpr size_t SZ_TAIL  = 2*SZ_RING + SZ_SPART + 4*SZ_FLAG + SZ_CST + SZ_MU;
constexpr int    ZERO_WORDS = (int)(4*SZ_FLAG / 4);        // flags only

// scan LDS: staging slabs (hi+lo, 64 x 264) alias per-step h area + sred
constexpr int SLAB_STRIDE = 264;
constexpr int HL_STRIDE   = 1040;
constexpr int SCAN_LDS    = 2 * 64 * SLAB_STRIDE * 2;      // 67584

__global__ void init_zero(unsigned* __restrict__ p, int n) {
    int i = blockIdx.x * blockDim.x + threadIdx.x;
    if (i < n) p[i] = 0u;
}

__device__ __forceinline__ void split_bf16(float v, bf16_t& hi, bf16_t& lo) {
    hi = (bf16_t)v;
    lo = (bf16_t)(v - (float)hi);
}

// ---------------- input-projection GEMM (split-precision bf16x2) ----------------
template<int KTOT, bool ROWMAP>
__global__ __launch_bounds__(256) void gemm_xp(
    const float* __restrict__ A,
    const float* __restrict__ W,
    const float* __restrict__ bias,
    float*       __restrict__ xp,
    int t0)
{
    __shared__ bf16_t Ash[64][40], Asl[64][40], Bsh[64][40], Bsl[64][40];
    const int bm = blockIdx.x / (ZDIM/64);
    const int bn = blockIdx.x % (ZDIM/64);
    const int tid  = threadIdx.x;
    const int lane = tid & 63;
    const int w    = tid >> 6;
    const int wm = w >> 1, wn = w & 1;
    const int q   = lane >> 4;
    const int l15 = lane & 15;

    f32x4 acc[2][2] = {};

    const int sm = tid & 63;
    const int sk = (tid >> 6) * 8;
    const int gr_glob = t0*32 + bm*64 + sm;
    const float* Arow;
    if constexpr (ROWMAP) {
        int tt = gr_glob >> 5, bb = gr_glob & 31;
        Arow = A + ((size_t)bb * T_STEPS + tt) * 256;
    } else {
        Arow = A + (size_t)gr_glob * HDIM;
    }
    const int gcol = bn*64 + sm;

    for (int k0 = 0; k0 < KTOT; k0 += 32) {
        {
            f32x4 a0 = *(const f32x4*)(Arow + k0 + sk);
            f32x4 a1 = *(const f32x4*)(Arow + k0 + sk + 4);
            #pragma unroll
            for (int j = 0; j < 4; ++j) {
                split_bf16(a0[j], Ash[sm][sk+j],   Asl[sm][sk+j]);
                split_bf16(a1[j], Ash[sm][sk+4+j], Asl[sm][sk+4+j]);
            }
        }
        #pragma unroll
        for (int j = 0; j < 8; ++j) {
            float wv = W[(size_t)(k0 + sk + j) * ZDIM + gcol];
            split_bf16(wv, Bsh[sm][sk+j], Bsl[sm][sk+j]);
        }
        __syncthreads();
        #pragma unroll
        for (int mt = 0; mt < 2; ++mt) {
            #pragma unroll
            for (int nt = 0; nt < 2; ++nt) {
                bf16x8 ah = *(const bf16x8*)&Ash[wm*32 + mt*16 + l15][q*8];
                bf16x8 al = *(const bf16x8*)&Asl[wm*32 + mt*16 + l15][q*8];
                bf16x8 bh = *(const bf16x8*)&Bsh[wn*32 + nt*16 + l15][q*8];
                bf16x8 bl = *(const bf16x8*)&Bsl[wn*32 + nt*16 + l15][q*8];
                acc[mt][nt] = __builtin_amdgcn_mfma_f32_16x16x32_bf16(ah, bh, acc[mt][nt], 0, 0, 0);
                acc[mt][nt] = __builtin_amdgcn_mfma_f32_16x16x32_bf16(al, bh, acc[mt][nt], 0, 0, 0);
                acc[mt][nt] = __builtin_amdgcn_mfma_f32_16x16x32_bf16(ah, bl, acc[mt][nt], 0, 0, 0);
            }
        }
        __syncthreads();
    }
    #pragma unroll
    for (int mt = 0; mt < 2; ++mt) {
        int row = bm*64 + wm*32 + mt*16 + q*4;
        #pragma unroll
        for (int nt = 0; nt < 2; ++nt) {
            int col = bn*64 + wn*32 + nt*16 + l15;
            float bia = bias[col];
            #pragma unroll
            for (int r = 0; r < 4; ++r)
                xp[(size_t)(row + r)*ZDIM + col] = acc[mt][nt][r] + bia;
        }
    }
}

// ---------------- persistent recurrent scan (flag-published sync) ----------------
// grid 256 x 256. group gid=blk>>6 owns batches 8*gid..+7; block lid=blk&63 owns
// h-cols H0=lid*16..+15. Recurrent W in registers as hi/lo bf16 A-fragments.
// MFMA C map: n=lane&15=batch, m=4q+reg -> reg=gate, hcl=4w+q. Lane-local cell update.
// Sync: per (t,block) write-once flags; publisher = plain data stores + release flag
// (same-wave vmcnt covers data); consumer = wave0 64-lane parallel poll + per-lane
// acquire (pairs with publisher l's release; transitive h-b via __syncthreads).
// Zero atomic RMWs in steady state (R3 was RMW-contention-bound at 28 us/step).
__global__ __launch_bounds__(256, 1) void scan_kernel(
    const float* __restrict__ Wh,     // [1024][4096] fp32 recurrent rows
    const float* __restrict__ xp,     // [cT*32][4096] fp32 chunk x-proj (incl bias)
    const float* __restrict__ gamma,
    const float* __restrict__ beta,
    float*       __restrict__ hring,  // [2][32][1024] fp32
    float*       __restrict__ hseq,   // [T*32][1024] fp32 or null (layer0)
    float*       __restrict__ outlast,// [32][1024] fp32 or null (layer1)
    float*       __restrict__ spart,  // [T][4][64][16] fp32 partials (no init needed)
    unsigned*    __restrict__ sflag,  // [T][4][64] (zeroed)
    unsigned*    __restrict__ hflag,  // [T][4][64] (zeroed)
    float*       __restrict__ cstate, // [32][1024] fp32
    float*       __restrict__ mustate,// [32] fp32
    int t0, int t1)
{
    extern __shared__ char smem[];
    bf16_t* slab_hi = (bf16_t*)smem;                         // [64][264] (W staging)
    bf16_t* slab_lo = (bf16_t*)(smem + 64*SLAB_STRIDE*2);
    bf16_t* hl_hi   = (bf16_t*)smem;                         // aliases slabs post-staging
    bf16_t* hl_lo   = (bf16_t*)(smem + 8*HL_STRIDE*2);
    float*  sred    = (float*) (smem + 16*HL_STRIDE*2);      // [144] f32

    const int gid = blockIdx.x >> 6;
    const int lid = blockIdx.x & 63;
    const int B0  = gid * 8;
    const int H0  = lid * 16;
    const int tid  = threadIdx.x;
    const int lane = tid & 63;
    const int w    = tid >> 6;
    const int q    = lane >> 4;
    const int l15  = lane & 15;

    // ---- stage recurrent W slice -> registers (hi/lo A-fragments) via LDS slabs ----
    bf16x8 wf_hi[32], wf_lo[32];
    {
        const int kw   = tid >> 6;
        const int strip= (tid >> 4) & 3;
        const int col  = tid & 15;
        const int gc2  = strip*1024 + H0 + col;
        const int rr_w = col*4 + strip;
        #pragma unroll
        for (int s = 0; s < 4; ++s) {
            for (int j = 0; j < 64; ++j) {
                int kk = j*4 + kw;
                float v = Wh[(size_t)(s*256 + kk)*ZDIM + gc2];
                bf16_t hi, lo; split_bf16(v, hi, lo);
                slab_hi[rr_w*SLAB_STRIDE + kk] = hi;
                slab_lo[rr_w*SLAB_STRIDE + kk] = lo;
            }
            __syncthreads();
            #pragma unroll
            for (int kbl = 0; kbl < 8; ++kbl) {
                wf_hi[s*8+kbl] = *(const bf16x8*)&slab_hi[(16*w + l15)*SLAB_STRIDE + kbl*32 + q*8];
                wf_lo[s*8+kbl] = *(const bf16x8*)&slab_lo[(16*w + l15)*SLAB_STRIDE + kbl*32 + q*8];
            }
            __syncthreads();
        }
    }

    const int  bidx  = l15;
    const bool valid = bidx < 8;
    const int  batch = B0 + bidx;
    const int  hcl   = 4*w + q;
    const int  hcg   = H0 + hcl;
    const float g_r = gamma[hcg];
    const float b_r = beta[hcg];
    const size_t xpbase = (size_t)batch * ZDIM + (size_t)H0 + hcl;
    const int hrow = (l15 < 8) ? l15 : 7;

    float c = 0.f, mu_prev = 0.f;
    if (t0 > 0 && valid) {
        c = cstate[(size_t)batch*HDIM + hcg];
        mu_prev = mustate[batch];
    }

    #pragma unroll 1
    for (int t = t0; t < t1; ++t) {
        // prefetch x-projection (issues before the wait; completes in its shadow)
        float xpv[4];
        {
            const float* xpt = xp + (size_t)(t - t0) * (BATCH*ZDIM) + xpbase;
            #pragma unroll
            for (int r = 0; r < 4; ++r) xpv[r] = valid ? xpt[(size_t)r * 1024] : 0.f;
        }
        f32x4 acc_hh = {0.f,0.f,0.f,0.f}, acc_lh = acc_hh, acc_hl = acc_hh;
        if (t > 0) {
            // ---- wait h(t-1): wave0 polls 64 flags in parallel ----
            if (w == 0) {
                const unsigned* hf = hflag + ((size_t)(t-1)*4 + gid)*64;
                unsigned f;
                do {
                    f = __hip_atomic_load(&hf[lane], __ATOMIC_RELAXED, __HIP_MEMORY_SCOPE_AGENT);
                } while (__ballot(f != 0u) != ~0ull);
                (void)__hip_atomic_load(&hf[lane], __ATOMIC_ACQUIRE, __HIP_MEMORY_SCOPE_AGENT);
            }
            __syncthreads();
            {   // stage h (fp32 -> hi/lo bf16) into LDS
                int row = tid >> 5;
                int li  = tid & 31;
                const float* hr = hring + (((size_t)((t-1)&1) * 32) + B0 + row) * HDIM;
                #pragma unroll
                for (int j = 0; j < 8; ++j) {
                    f32x4 v = ((const f32x4*)hr)[li + j*32];
                    bf16x4 bh, bl;
                    #pragma unroll
                    for (int e = 0; e < 4; ++e) { bf16_t hi, lo; split_bf16(v[e], hi, lo); bh[e]=hi; bl[e]=lo; }
                    *(bf16x4*)&hl_hi[row*HL_STRIDE + (li + j*32)*4] = bh;
                    *(bf16x4*)&hl_lo[row*HL_STRIDE + (li + j*32)*4] = bl;
                }
            }
            __syncthreads();
            const bf16_t* Bh = hl_hi + (size_t)hrow * HL_STRIDE + q*8;
            const bf16_t* Bl = hl_lo + (size_t)hrow * HL_STRIDE + q*8;
            #pragma unroll
            for (int kb = 0; kb < 32; ++kb) {
                bf16x8 bh = *(const bf16x8*)(Bh + kb*32);
                bf16x8 bl = *(const bf16x8*)(Bl + kb*32);
                acc_hh = __builtin_amdgcn_mfma_f32_16x16x32_bf16(wf_hi[kb], bh, acc_hh, 0, 0, 0);
                acc_lh = __builtin_amdgcn_mfma_f32_16x16x32_bf16(wf_lo[kb], bh, acc_lh, 0, 0, 0);
                acc_hl = __builtin_amdgcn_mfma_f32_16x16x32_bf16(wf_hi[kb], bl, acc_hl, 0, 0, 0);
            }
        }
        float z[4];
        #pragma unroll
        for (int r = 0; r < 4; ++r)
            z[r] = ((acc_lh[r] + acc_hl[r]) + acc_hh[r]) + xpv[r];
        float zi = fminf(fmaxf(z[0], -6.f), 3.f);
        float zf = fminf(fmaxf(z[1], -6.f), 3.f);
        float ig = __expf(zi);
        float fg = __expf(zf);
        float cand = tanhf(z[2]);
        float sg = 1.f / (1.f + __expf(-z[3]));
        c = fg * c + ig * cand;

        // ---- LN stats: wave partials -> block partial -> publish -> all-group reduce
        float dm = valid ? (c - mu_prev) : 0.f;
        float s1 = dm, s2 = dm * dm;
        s1 += __shfl_xor(s1, 16); s2 += __shfl_xor(s2, 16);
        s1 += __shfl_xor(s1, 32); s2 += __shfl_xor(s2, 32);
        if (q == 0) { sred[(w*16 + l15)*2] = s1; sred[(w*16 + l15)*2 + 1] = s2; }
        __syncthreads();
        if (w == 0) {
            // block partial (8 batches x 2) from 4 wave partials; publish 64 B + flag
            if (q == 0 && l15 < 8) {
                float S1 = 0.f, S2 = 0.f;
                #pragma unroll
                for (int ww = 0; ww < 4; ++ww) {
                    S1 += sred[(ww*16 + l15)*2];
                    S2 += sred[(ww*16 + l15)*2 + 1];
                }
                float* sp = spart + (((size_t)t*4 + gid)*64 + lid)*16 + l15*2;
                sp[0] = S1; sp[1] = S2;
            }
            unsigned* sf = sflag + ((size_t)t*4 + gid)*64;
            if (lane == 0)   // same wave as data stores -> vmcnt drain covers them
                __hip_atomic_store(&sf[lid], 1u, __ATOMIC_RELEASE, __HIP_MEMORY_SCOPE_AGENT);
            // poll all 64 block flags in parallel
            unsigned f;
            do {
                f = __hip_atomic_load(&sf[lane], __ATOMIC_RELAXED, __HIP_MEMORY_SCOPE_AGENT);
            } while (__ballot(f != 0u) != ~0ull);
            (void)__hip_atomic_load(&sf[lane], __ATOMIC_ACQUIRE, __HIP_MEMORY_SCOPE_AGENT);
            // lane l reads block l's 16-float slot; butterfly-sum across 64 lanes
            const float* sb = spart + (((size_t)t*4 + gid)*64 + lane)*16;
            f32x4 p0 = *(const f32x4*)(sb);
            f32x4 p1 = *(const f32x4*)(sb + 4);
            f32x4 p2 = *(const f32x4*)(sb + 8);
            f32x4 p3 = *(const f32x4*)(sb + 12);
            #pragma unroll
            for (int m = 1; m < 64; m <<= 1) {
                #pragma unroll
                for (int e = 0; e < 4; ++e) {
                    p0[e] += __shfl_xor(p0[e], m);
                    p1[e] += __shfl_xor(p1[e], m);
                    p2[e] += __shfl_xor(p2[e], m);
                    p3[e] += __shfl_xor(p3[e], m);
                }
            }
            // totals -> LDS slots 128..143 (disjoint from partials 0..127)
            if (lane < 4)  sred[128 + lane]      = p0[lane];
            else if (lane < 8)  sred[128 + lane] = p1[lane-4];
            else if (lane < 12) sred[128 + lane] = p2[lane-8];
            else if (lane < 16) sred[128 + lane] = p3[lane-12];
        }
        __syncthreads();
        if (valid) {
            float S1 = sred[128 + bidx*2];
            float S2 = sred[128 + bidx*2 + 1];
            float dmu = S1 * (1.f/1024.f);
            float mu  = mu_prev + dmu;
            float var = S2 * (1.f/1024.f) - dmu*dmu;
            float ln  = (c - mu) * rsqrtf(var + 1e-5f) * g_r + b_r;
            float hv  = sg * tanhf(ln);
            mu_prev = mu;
            hring[((size_t)(t&1)*32 + batch)*HDIM + hcg] = hv;
            if (hseq)    hseq[((size_t)t*32 + batch)*HDIM + hcg] = hv;
            if (outlast && t == T_STEPS-1) outlast[(size_t)batch*HDIM + hcg] = hv;
        }
        __syncthreads();  // barrier drains vmcnt: all waves' h stores complete
        if (tid == 0)
            __hip_atomic_store(&hflag[((size_t)t*4 + gid)*64 + lid], 1u,
                               __ATOMIC_RELEASE, __HIP_MEMORY_SCOPE_AGENT);
    }

    if (t1 < T_STEPS) {
        if (valid) cstate[(size_t)batch*HDIM + hcg] = c;
        if (lid == 0 && w == 0 && q == 0 && l15 < 8) mustate[B0 + l15] = mu_prev;
    }
}

extern "C" void kernel_launch(void* const* d_in, const int* in_sizes, int n_in,
                              void* d_out, int out_size, void* d_ws, size_t ws_size,
                              hipStream_t stream) {
    (void)in_sizes; (void)n_in;
    const float* series = (const float*)d_in[0];
    const float* W0  = (const float*)d_in[1];
    const float* b0  = (const float*)d_in[2];
    const float* g0  = (const float*)d_in[3];
    const float* be0 = (const float*)d_in[4];
    const float* W1  = (const float*)d_in[5];
    const float* b1  = (const float*)d_in[6];
    const float* g1  = (const float*)d_in[7];
    const float* be1 = (const float*)d_in[8];
    float* out = (float*)d_out;
    unsigned char* ws = (unsigned char*)d_ws;

    // pick the largest time-chunk whose fp32 xp buffer fits the workspace
    int cT = 0;
    const int cands[5] = {256, 128, 64, 32, 16};
    for (int i = 0; i < 5; ++i) {
        size_t need = (size_t)cands[i]*32*ZDIM*4 + SZ_H0 + SZ_TAIL;
        if (need <= ws_size) { cT = cands[i]; break; }
    }
    if (cT == 0) {
        (void)hipMemsetAsync(d_out, 0, (size_t)out_size * sizeof(float), stream);
        return;
    }
    const size_t sz_xp = (size_t)cT*32*ZDIM*4;
    unsigned char* p = ws;
    float*    xp     = (float*)p;            p += sz_xp;
    float*    h0seq  = (float*)p;            p += SZ_H0;
    float*    hring0 = (float*)p;            p += SZ_RING;
    float*    hring1 = (float*)p;            p += SZ_RING;
    float*    spart  = (float*)p;            p += SZ_SPART;  // shared by both layers
    unsigned* sflag0 = (unsigned*)p;         p += SZ_FLAG;   // flags: zeroed below
    unsigned* sflag1 = (unsigned*)p;         p += SZ_FLAG;
    unsigned* hflag0 = (unsigned*)p;         p += SZ_FLAG;
    unsigned* hflag1 = (unsigned*)p;         p += SZ_FLAG;
    float*    cstate = (float*)p;            p += SZ_CST;
    float*    mustate= (float*)p;

    (void)hipFuncSetAttribute((const void*)scan_kernel,
                              hipFuncAttributeMaxDynamicSharedMemorySize, SCAN_LDS);

    init_zero<<<(ZERO_WORDS + 255)/256, 256, 0, stream>>>(sflag0, ZERO_WORDS);

    const int nch = T_STEPS / cT;
    const int gemm_grid = (cT*32/64) * (ZDIM/64);

    // ---- layer 0 ----
    for (int ci = 0; ci < nch; ++ci) {
        int t0 = ci*cT, t1 = t0 + cT;
        gemm_xp<256, true><<<gemm_grid, 256, 0, stream>>>(series, W0, b0, xp, t0);
        scan_kernel<<<256, 256, SCAN_LDS, stream>>>(
            W0 + (size_t)256*ZDIM, xp, g0, be0, hring0, h0seq, nullptr,
            spart, sflag0, hflag0, cstate, mustate, t0, t1);
    }
    // ---- layer 1 ----
    for (int ci = 0; ci < nch; ++ci) {
        int t0 = ci*cT, t1 = t0 + cT;
        gemm_xp<1024, false><<<gemm_grid, 256, 0, stream>>>(h0seq, W1, b1, xp, t0);
        scan_kernel<<<256, 256, SCAN_LDS, stream>>>(
            W1 + (size_t)1024*ZDIM, xp, g1, be1, hring1, nullptr, out,
            spart, sflag1, hflag1, cstate, mustate, t0, t1);
    }
}

// Round 5
// 9000.235 us; speedup vs baseline: 1.5718x; 1.2377x over previous
//
#include <hip/hip_runtime.h>
#include <hip/hip_bf16.h>
#include <cstddef>

typedef __bf16 bf16_t;
typedef bf16_t bf16x8 __attribute__((ext_vector_type(8)));
typedef bf16_t bf16x4 __attribute__((ext_vector_type(4)));
typedef float  f32x4  __attribute__((ext_vector_type(4)));

#define T_STEPS 256
#define BATCH   32
#define HDIM    1024
#define ZDIM    4096

// ---------------- workspace sizes ----------------
constexpr size_t SZ_HSEQ  = (size_t)8192 * 1024 * 2;       // 16 MiB (hi or lo)
constexpr size_t SZ_CPUB  = (size_t)2 * 32 * 1024 * 4;     // 256 KiB
constexpr size_t SZ_PART  = (size_t)2 * 4 * 64 * 16 * 4;   // 32 KiB
constexpr size_t SZ_FLAG  = (size_t)256 * 4 * 64 * 4;      // 256 KiB per layer
constexpr size_t SZ_HST   = (size_t)32 * 1024 * 2;         // 64 KiB (hi or lo)
constexpr size_t SZ_CST   = (size_t)32 * 1024 * 4;         // 128 KiB
constexpr size_t SZ_MU    = 256;
constexpr size_t SZ_TAIL  = 2*SZ_CPUB + SZ_PART + 2*SZ_FLAG + 2*SZ_HST + SZ_CST + SZ_MU;
constexpr int    ZERO_WORDS = (int)(2*SZ_FLAG / 4);

// ---------------- LDS ----------------
constexpr int SLAB_STRIDE = 264;                 // W staging rows (bf16)
constexpr int HL_STRIDE   = 1040;                // h rows (bf16), 2080 B
// post-staging map: hl_hi [8][1040] @0, hl_lo @16640, gl @33280, bl @37376,
// sred[4][16][2] @41472, stot[16] @41984  -- all inside the 67584 slab region
constexpr int SCAN_LDS    = 2 * 64 * SLAB_STRIDE * 2;  // 67584

__global__ void init_zero(unsigned* __restrict__ p, int n) {
    int i = blockIdx.x * blockDim.x + threadIdx.x;
    if (i < n) p[i] = 0u;
}

__device__ __forceinline__ void split_bf16(float v, bf16_t& hi, bf16_t& lo) {
    hi = (bf16_t)v;
    lo = (bf16_t)(v - (float)hi);
}

// ---------------- input-projection GEMM (split-precision bf16x2) ----------------
// MODE 0: A fp32 with series row-remap (layer0, K=256)
// MODE 1: A pre-split hi/lo bf16 (layer1, K=1024)
template<int KTOT, int MODE>
__global__ __launch_bounds__(256) void gemm_xp(
    const float*  __restrict__ Afp,
    const bf16_t* __restrict__ Ahi,
    const bf16_t* __restrict__ Alo,
    const float*  __restrict__ W,
    const float*  __restrict__ bias,
    float*        __restrict__ xp,
    int t0)
{
    __shared__ bf16_t Ash[64][40], Asl[64][40], Bsh[64][40], Bsl[64][40];
    const int bm = blockIdx.x / (ZDIM/64);
    const int bn = blockIdx.x % (ZDIM/64);
    const int tid  = threadIdx.x;
    const int lane = tid & 63;
    const int w    = tid >> 6;
    const int wm = w >> 1, wn = w & 1;
    const int q   = lane >> 4;
    const int l15 = lane & 15;

    f32x4 acc[2][2] = {};

    const int sm = tid & 63;
    const int sk = (tid >> 6) * 8;
    const int gr = t0*32 + bm*64 + sm;
    const float*  Arow  = nullptr;
    const bf16_t* Ahrow = nullptr;
    const bf16_t* Alrow = nullptr;
    if constexpr (MODE == 0) {
        int tt = gr >> 5, bb = gr & 31;
        Arow = Afp + ((size_t)bb * T_STEPS + tt) * 256;
    } else {
        Ahrow = Ahi + (size_t)gr * HDIM;
        Alrow = Alo + (size_t)gr * HDIM;
    }
    const int gcol = bn*64 + sm;

    for (int k0 = 0; k0 < KTOT; k0 += 32) {
        if constexpr (MODE == 0) {
            f32x4 a0 = *(const f32x4*)(Arow + k0 + sk);
            f32x4 a1 = *(const f32x4*)(Arow + k0 + sk + 4);
            #pragma unroll
            for (int j = 0; j < 4; ++j) {
                split_bf16(a0[j], Ash[sm][sk+j],   Asl[sm][sk+j]);
                split_bf16(a1[j], Ash[sm][sk+4+j], Asl[sm][sk+4+j]);
            }
        } else {
            *(bf16x8*)&Ash[sm][sk] = *(const bf16x8*)(Ahrow + k0 + sk);
            *(bf16x8*)&Asl[sm][sk] = *(const bf16x8*)(Alrow + k0 + sk);
        }
        #pragma unroll
        for (int j = 0; j < 8; ++j) {
            float wv = W[(size_t)(k0 + sk + j) * ZDIM + gcol];
            split_bf16(wv, Bsh[sm][sk+j], Bsl[sm][sk+j]);
        }
        __syncthreads();
        #pragma unroll
        for (int mt = 0; mt < 2; ++mt) {
            #pragma unroll
            for (int nt = 0; nt < 2; ++nt) {
                bf16x8 ah = *(const bf16x8*)&Ash[wm*32 + mt*16 + l15][q*8];
                bf16x8 al = *(const bf16x8*)&Asl[wm*32 + mt*16 + l15][q*8];
                bf16x8 bh = *(const bf16x8*)&Bsh[wn*32 + nt*16 + l15][q*8];
                bf16x8 bl = *(const bf16x8*)&Bsl[wn*32 + nt*16 + l15][q*8];
                acc[mt][nt] = __builtin_amdgcn_mfma_f32_16x16x32_bf16(ah, bh, acc[mt][nt], 0, 0, 0);
                acc[mt][nt] = __builtin_amdgcn_mfma_f32_16x16x32_bf16(al, bh, acc[mt][nt], 0, 0, 0);
                acc[mt][nt] = __builtin_amdgcn_mfma_f32_16x16x32_bf16(ah, bl, acc[mt][nt], 0, 0, 0);
            }
        }
        __syncthreads();
    }
    #pragma unroll
    for (int mt = 0; mt < 2; ++mt) {
        int row = bm*64 + wm*32 + mt*16 + q*4;
        #pragma unroll
        for (int nt = 0; nt < 2; ++nt) {
            int col = bn*64 + wn*32 + nt*16 + l15;
            float bia = bias[col];
            #pragma unroll
            for (int r = 0; r < 4; ++r)
                xp[(size_t)(row + r)*ZDIM + col] = acc[mt][nt][r] + bia;
        }
    }
}

// ---------------- persistent recurrent scan: ONE rendezvous/step, NO wbl2/inv ----
// grid 256 x 256. group gid=blk>>6 owns batches 8*gid..+7; block lid=blk&63 owns
// h-cols H0=lid*16..+15. W in register hi/lo bf16 A-fragments.
// Per step: MFMA(h(t-1) from LDS) -> gates -> publish c,sg (volatile sc0sc1) +
// stat partials -> flag (relaxed agent, no wbl2) -> wave0 polls 64 flags ->
// totals via butterfly -> ALL blocks compute LN+h during staging (redundant but
// removes the 2nd rendezvous). R4 was L2-maintenance-bound (wbl2/inv serialization).
__global__ __launch_bounds__(256, 1) void scan_kernel(
    const float* __restrict__ Wh,      // [1024][4096] fp32 recurrent rows
    const float* __restrict__ xp,      // [cT*32][4096] fp32 x-proj (incl bias)
    const float* __restrict__ gamma,
    const float* __restrict__ beta,
    float*       cpub,                 // [2][32][1024] fp32 (coherent)
    float*       spub,                 // [2][32][1024] fp32 (coherent)
    float*       part,                 // [2][4][64][16] fp32 (coherent)
    unsigned*    flag,                 // [T][4][64] (zeroed)
    bf16_t*      __restrict__ hseq_hi, // [T*32][1024] or null (layer0)
    bf16_t*      __restrict__ hseq_lo,
    float*       __restrict__ outlast, // [32][1024] or null (layer1)
    bf16_t*      __restrict__ hst_hi,  // [32][1024] chunk-carry
    bf16_t*      __restrict__ hst_lo,
    float*       __restrict__ cstate,  // [32][1024]
    float*       __restrict__ mustate, // [32]
    int t0, int t1)
{
    extern __shared__ char smem[];
    bf16_t* slab_hi = (bf16_t*)smem;                       // W staging
    bf16_t* slab_lo = (bf16_t*)(smem + 64*SLAB_STRIDE*2);
    bf16_t* hl_hi   = (bf16_t*)smem;                       // [8][1040] post-staging
    bf16_t* hl_lo   = (bf16_t*)(smem + 8*HL_STRIDE*2);
    float*  gl      = (float*)(smem + 16*HL_STRIDE*2);     // [1024]
    float*  bl      = gl + 1024;                           // [1024]
    float*  sred    = bl + 1024;                           // [4][16][2]
    float*  stot    = sred + 128;                          // [16]

    const int gid = blockIdx.x >> 6;
    const int lid = blockIdx.x & 63;
    const int B0  = gid * 8;
    const int H0  = lid * 16;
    const int tid  = threadIdx.x;
    const int lane = tid & 63;
    const int w    = tid >> 6;
    const int q    = lane >> 4;
    const int l15  = lane & 15;

    // ---- stage recurrent W slice -> registers (hi/lo A-fragments) via LDS slabs
    bf16x8 wf_hi[32], wf_lo[32];
    {
        const int kw   = tid >> 6;
        const int strip= (tid >> 4) & 3;
        const int col  = tid & 15;
        const int gc2  = strip*1024 + H0 + col;
        const int rr_w = col*4 + strip;
        #pragma unroll
        for (int s = 0; s < 4; ++s) {
            for (int j = 0; j < 64; ++j) {
                int kk = j*4 + kw;
                float v = Wh[(size_t)(s*256 + kk)*ZDIM + gc2];
                bf16_t hi, lo; split_bf16(v, hi, lo);
                slab_hi[rr_w*SLAB_STRIDE + kk] = hi;
                slab_lo[rr_w*SLAB_STRIDE + kk] = lo;
            }
            __syncthreads();
            #pragma unroll
            for (int kbl = 0; kbl < 8; ++kbl) {
                wf_hi[s*8+kbl] = *(const bf16x8*)&slab_hi[(16*w + l15)*SLAB_STRIDE + kbl*32 + q*8];
                wf_lo[s*8+kbl] = *(const bf16x8*)&slab_lo[(16*w + l15)*SLAB_STRIDE + kbl*32 + q*8];
            }
            __syncthreads();
        }
    }
    // gamma/beta -> LDS (slab region is dead now)
    for (int i = tid; i < 1024; i += 256) { gl[i] = gamma[i]; bl[i] = beta[i]; }

    const int  bidx  = l15;
    const bool valid = bidx < 8;
    const int  batch = B0 + bidx;
    const int  hcl   = 4*w + q;
    const int  hcg   = H0 + hcl;
    const size_t xpbase = (size_t)batch * ZDIM + (size_t)H0 + hcl;
    const int hrow  = (l15 < 8) ? l15 : 7;
    const int srow  = tid >> 5;     // staging row 0..7
    const int sli   = tid & 31;
    const int sbatch= B0 + srow;

    float c = 0.f, mu_pub = 0.f, mu_stg = 0.f;
    if (t0 > 0) {
        if (valid) c = cstate[(size_t)batch*HDIM + hcg];
        mu_pub = mustate[B0 + (bidx & 7)];
        mu_stg = mustate[sbatch];
        // prologue: stage h(t0-1) from chunk-carry
        #pragma unroll
        for (int j = 0; j < 8; ++j) {
            int d0 = (sli + j*32)*4;
            *(bf16x4*)&hl_hi[srow*HL_STRIDE + d0] = *(const bf16x4*)&hst_hi[(size_t)sbatch*HDIM + d0];
            *(bf16x4*)&hl_lo[srow*HL_STRIDE + d0] = *(const bf16x4*)&hst_lo[(size_t)sbatch*HDIM + d0];
        }
    }
    __syncthreads();

    #pragma unroll 1
    for (int t = t0; t < t1; ++t) {
        // xp prefetch (independent of rendezvous)
        float xpv[4];
        {
            const float* xpt = xp + (size_t)(t - t0) * (BATCH*ZDIM) + xpbase;
            #pragma unroll
            for (int r = 0; r < 4; ++r) xpv[r] = valid ? xpt[(size_t)r * 1024] : 0.f;
        }
        f32x4 acc_hh = {0.f,0.f,0.f,0.f}, acc_lh = acc_hh, acc_hl = acc_hh;
        if (t > 0) {
            const bf16_t* Bh = hl_hi + (size_t)hrow * HL_STRIDE + q*8;
            const bf16_t* Bl = hl_lo + (size_t)hrow * HL_STRIDE + q*8;
            #pragma unroll
            for (int kb = 0; kb < 32; ++kb) {
                bf16x8 bh = *(const bf16x8*)(Bh + kb*32);
                bf16x8 bv = *(const bf16x8*)(Bl + kb*32);
                acc_hh = __builtin_amdgcn_mfma_f32_16x16x32_bf16(wf_hi[kb], bh, acc_hh, 0, 0, 0);
                acc_lh = __builtin_amdgcn_mfma_f32_16x16x32_bf16(wf_lo[kb], bh, acc_lh, 0, 0, 0);
                acc_hl = __builtin_amdgcn_mfma_f32_16x16x32_bf16(wf_hi[kb], bv, acc_hl, 0, 0, 0);
            }
        }
        float z[4];
        #pragma unroll
        for (int r = 0; r < 4; ++r)
            z[r] = ((acc_lh[r] + acc_hl[r]) + acc_hh[r]) + xpv[r];
        float zi = fminf(fmaxf(z[0], -6.f), 3.f);
        float zf = fminf(fmaxf(z[1], -6.f), 3.f);
        float ig = __expf(zi);
        float fg = __expf(zf);
        float cand = tanhf(z[2]);
        float sg = 1.f / (1.f + __expf(-z[3]));
        c = fg * c + ig * cand;

        // ---- publish c, sg (coherent volatile stores: sc0 sc1, no wbl2)
        const int par = t & 1;
        if (valid) {
            *(volatile float*)(cpub + ((size_t)par*32 + batch)*HDIM + hcg) = c;
            *(volatile float*)(spub + ((size_t)par*32 + batch)*HDIM + hcg) = sg;
        }
        // wave stat partials (shifted by mu_pub)
        float dm = valid ? (c - mu_pub) : 0.f;
        float s1 = dm, s2 = dm * dm;
        s1 += __shfl_xor(s1, 16); s2 += __shfl_xor(s2, 16);
        s1 += __shfl_xor(s1, 32); s2 += __shfl_xor(s2, 32);
        if (q == 0 && l15 < 8) { sred[(w*16 + l15)*2] = s1; sred[(w*16 + l15)*2 + 1] = s2; }
        __syncthreads();   // B1: sred ready; all waves' c/sg stores drained

        unsigned* fl = flag + ((size_t)t*4 + gid)*64;
        if (w == 0) {
            if (lane < 16) {
                int b = lane >> 1, comp = lane & 1;
                float P = sred[(0*16+b)*2+comp] + sred[(1*16+b)*2+comp]
                        + sred[(2*16+b)*2+comp] + sred[(3*16+b)*2+comp];
                *(volatile float*)(part + (((size_t)par*4 + gid)*64 + lid)*16 + lane) = P;
            }
            asm volatile("s_waitcnt vmcnt(0)" ::: "memory");
            if (lane == 0)
                __hip_atomic_store(&fl[lid], 1u, __ATOMIC_RELAXED, __HIP_MEMORY_SCOPE_AGENT);
            // single rendezvous: poll all 64 block flags for step t
            for (;;) {
                unsigned f = __hip_atomic_load(&fl[lane], __ATOMIC_RELAXED, __HIP_MEMORY_SCOPE_AGENT);
                if (__ballot(f != 0u) == ~0ull) break;
                __builtin_amdgcn_s_sleep(1);
            }
            // totals: lane reads block `lane`'s 16 partials, butterfly-sum
            volatile const f32x4* pb = (volatile const f32x4*)(part + (((size_t)par*4 + gid)*64 + lane)*16);
            f32x4 p0 = pb[0], p1 = pb[1], p2 = pb[2], p3 = pb[3];
            #pragma unroll
            for (int m = 1; m < 64; m <<= 1) {
                #pragma unroll
                for (int e = 0; e < 4; ++e) {
                    p0[e] += __shfl_xor(p0[e], m);
                    p1[e] += __shfl_xor(p1[e], m);
                    p2[e] += __shfl_xor(p2[e], m);
                    p3[e] += __shfl_xor(p3[e], m);
                }
            }
            if (lane == 0) {
                *(f32x4*)&stot[0]  = p0;
                *(f32x4*)&stot[4]  = p1;
                *(f32x4*)&stot[8]  = p2;
                *(f32x4*)&stot[12] = p3;
            }
        }
        __syncthreads();   // B2: stot ready

        // per-thread LN params (fixed batch indices -> no reg indexing)
        float dmu_s = stot[2*srow] * (1.f/1024.f);
        float mu_s  = mu_stg + dmu_s;
        float var_s = stot[2*srow+1] * (1.f/1024.f) - dmu_s*dmu_s;
        float rsig  = rsqrtf(var_s + 1e-5f);
        mu_stg = mu_s;
        mu_pub += stot[2*(bidx & 7)] * (1.f/1024.f);

        // ---- staging: read c,sg (coherent), compute h, split hi/lo -> LDS
        volatile const f32x4* crow = (volatile const f32x4*)(cpub + ((size_t)par*32 + sbatch)*HDIM);
        volatile const f32x4* grow = (volatile const f32x4*)(spub + ((size_t)par*32 + sbatch)*HDIM);
        const bool wr_seq = (hseq_hi != nullptr) && (lid == srow);
        const bool wr_hst = (t == t1-1) && (t1 < T_STEPS) && (lid == srow);
        const bool wr_out = (outlast != nullptr) && (t == T_STEPS-1) && (lid == srow);
        #pragma unroll 2
        for (int j = 0; j < 8; ++j) {
            int d0 = (sli + j*32)*4;
            f32x4 cv = crow[sli + j*32];
            f32x4 sv = grow[sli + j*32];
            f32x4 hv;
            bf16x4 bh, blo;
            #pragma unroll
            for (int e = 0; e < 4; ++e) {
                float ln = (cv[e] - mu_s) * rsig * gl[d0+e] + bl[d0+e];
                float h  = sv[e] * tanhf(ln);
                hv[e] = h;
                bf16_t hi, lo; split_bf16(h, hi, lo);
                bh[e] = hi; blo[e] = lo;
            }
            *(bf16x4*)&hl_hi[srow*HL_STRIDE + d0] = bh;
            *(bf16x4*)&hl_lo[srow*HL_STRIDE + d0] = blo;
            if (wr_seq) {
                *(bf16x4*)&hseq_hi[((size_t)t*32 + sbatch)*HDIM + d0] = bh;
                *(bf16x4*)&hseq_lo[((size_t)t*32 + sbatch)*HDIM + d0] = blo;
            }
            if (wr_hst) {
                *(bf16x4*)&hst_hi[(size_t)sbatch*HDIM + d0] = bh;
                *(bf16x4*)&hst_lo[(size_t)sbatch*HDIM + d0] = blo;
            }
            if (wr_out) *(f32x4*)&outlast[(size_t)sbatch*HDIM + d0] = hv;
        }
        __syncthreads();   // B3: hl ready for next step's MFMA
    }

    // chunk-carry state
    if (t1 < T_STEPS) {
        if (valid) cstate[(size_t)batch*HDIM + hcg] = c;
        if (lid == 0 && sli == 0) mustate[sbatch] = mu_stg;
    }
}

extern "C" void kernel_launch(void* const* d_in, const int* in_sizes, int n_in,
                              void* d_out, int out_size, void* d_ws, size_t ws_size,
                              hipStream_t stream) {
    (void)in_sizes; (void)n_in;
    const float* series = (const float*)d_in[0];
    const float* W0  = (const float*)d_in[1];
    const float* b0  = (const float*)d_in[2];
    const float* g0  = (const float*)d_in[3];
    const float* be0 = (const float*)d_in[4];
    const float* W1  = (const float*)d_in[5];
    const float* b1  = (const float*)d_in[6];
    const float* g1  = (const float*)d_in[7];
    const float* be1 = (const float*)d_in[8];
    float* out = (float*)d_out;
    unsigned char* ws = (unsigned char*)d_ws;

    int cT = 0;
    const int cands[4] = {256, 128, 64, 32};
    for (int i = 0; i < 4; ++i) {
        size_t need = (size_t)cands[i]*32*ZDIM*4 + 2*SZ_HSEQ + SZ_TAIL;
        if (need <= ws_size) { cT = cands[i]; break; }
    }
    if (cT == 0) {
        (void)hipMemsetAsync(d_out, 0, (size_t)out_size * sizeof(float), stream);
        return;
    }
    const size_t sz_xp = (size_t)cT*32*ZDIM*4;
    unsigned char* p = ws;
    float*    xp      = (float*)p;    p += sz_xp;
    bf16_t*   hseq_hi = (bf16_t*)p;   p += SZ_HSEQ;
    bf16_t*   hseq_lo = (bf16_t*)p;   p += SZ_HSEQ;
    float*    cpub    = (float*)p;    p += SZ_CPUB;
    float*    spub    = (float*)p;    p += SZ_CPUB;
    float*    part    = (float*)p;    p += SZ_PART;
    unsigned* flag0   = (unsigned*)p; p += SZ_FLAG;
    unsigned* flag1   = (unsigned*)p; p += SZ_FLAG;
    bf16_t*   hst_hi  = (bf16_t*)p;   p += SZ_HST;
    bf16_t*   hst_lo  = (bf16_t*)p;   p += SZ_HST;
    float*    cstate  = (float*)p;    p += SZ_CST;
    float*    mustate = (float*)p;

    (void)hipFuncSetAttribute((const void*)scan_kernel,
                              hipFuncAttributeMaxDynamicSharedMemorySize, SCAN_LDS);

    init_zero<<<(ZERO_WORDS + 255)/256, 256, 0, stream>>>(flag0, ZERO_WORDS);

    const int nch = T_STEPS / cT;
    const int gemm_grid = (cT*32/64) * (ZDIM/64);

    // ---- layer 0 ----
    for (int ci = 0; ci < nch; ++ci) {
        int t0 = ci*cT, t1 = t0 + cT;
        gemm_xp<256, 0><<<gemm_grid, 256, 0, stream>>>(
            series, nullptr, nullptr, W0, b0, xp, t0);
        scan_kernel<<<256, 256, SCAN_LDS, stream>>>(
            W0 + (size_t)256*ZDIM, xp, g0, be0, cpub, spub, part, flag0,
            hseq_hi, hseq_lo, nullptr, hst_hi, hst_lo, cstate, mustate, t0, t1);
    }
    // ---- layer 1 ----
    for (int ci = 0; ci < nch; ++ci) {
        int t0 = ci*cT, t1 = t0 + cT;
        gemm_xp<1024, 1><<<gemm_grid, 256, 0, stream>>>(
            nullptr, hseq_hi, hseq_lo, W1, b1, xp, t0);
        scan_kernel<<<256, 256, SCAN_LDS, stream>>>(
            W1 + (size_t)1024*ZDIM, xp, g1, be1, cpub, spub, part, flag1,
            nullptr, nullptr, out, hst_hi, hst_lo, cstate, mustate, t0, t1);
    }
}

// Round 6
// 7232.728 us; speedup vs baseline: 1.9559x; 1.2444x over previous
//
#include <hip/hip_runtime.h>
#include <hip/hip_bf16.h>
#include <cstddef>

typedef __bf16 bf16_t;
typedef bf16_t bf16x8 __attribute__((ext_vector_type(8)));
typedef bf16_t bf16x4 __attribute__((ext_vector_type(4)));
typedef float  f32x4  __attribute__((ext_vector_type(4)));
typedef unsigned u32x4 __attribute__((ext_vector_type(4)));

#define T_STEPS 256
#define BATCH   32
#define HDIM    1024
#define ZDIM    4096

// ---------------- workspace sizes ----------------
constexpr size_t SZ_HSEQ  = (size_t)8192 * 1024 * 2;       // 16 MiB (hi or lo)
constexpr size_t SZ_HPUB  = (size_t)2 * 32 * 1024 * 4;     // 256 KiB packed h
constexpr size_t SZ_PART  = (size_t)2 * 4 * 64 * 16 * 4;   // 32 KiB
constexpr size_t SZ_FLAG  = (size_t)256 * 4 * 64 * 4;      // 256 KiB per array
constexpr size_t SZ_HST   = (size_t)32 * 1024 * 2;         // 64 KiB (hi or lo)
constexpr size_t SZ_CST   = (size_t)32 * 1024 * 4;         // 128 KiB
constexpr size_t SZ_MU    = 256;
constexpr size_t SZ_TAIL  = SZ_HPUB + SZ_PART + 4*SZ_FLAG + 2*SZ_HST + SZ_CST + SZ_MU;
constexpr int    ZERO_WORDS = (int)(4*SZ_FLAG / 4);

// ---------------- LDS ----------------
constexpr int SLAB_STRIDE = 264;                 // W staging rows (bf16)
constexpr int HL_STRIDE   = 1040;                // h rows (bf16), 2080 B
// post-staging: hl_hi [8][1040] @0, hl_lo @16640, sred[128] @33280, stot[16] @33792
constexpr int SCAN_LDS    = 2 * 64 * SLAB_STRIDE * 2;  // 67584

__global__ void init_zero(unsigned* __restrict__ p, int n) {
    int i = blockIdx.x * blockDim.x + threadIdx.x;
    if (i < n) p[i] = 0u;
}

__device__ __forceinline__ void split_bf16(float v, bf16_t& hi, bf16_t& lo) {
    hi = (bf16_t)v;
    lo = (bf16_t)(v - (float)hi);
}
__device__ __forceinline__ unsigned short bf16_bits(bf16_t f) {
    union { unsigned short u; bf16_t f2; } x; x.f2 = f; return x.u;
}
__device__ __forceinline__ bf16_t bf16_from_bits(unsigned short b) {
    union { unsigned short u; bf16_t f2; } x; x.u = b; return x.f2;
}

// ---------------- input-projection GEMM (split-precision bf16x2) ----------------
// MODE 0: A fp32 with series row-remap (layer0, K=256)
// MODE 1: A pre-split hi/lo bf16 (layer1, K=1024)
template<int KTOT, int MODE>
__global__ __launch_bounds__(256) void gemm_xp(
    const float*  __restrict__ Afp,
    const bf16_t* __restrict__ Ahi,
    const bf16_t* __restrict__ Alo,
    const float*  __restrict__ W,
    const float*  __restrict__ bias,
    float*        __restrict__ xp,
    int t0)
{
    __shared__ bf16_t Ash[64][40], Asl[64][40], Bsh[64][40], Bsl[64][40];
    const int bm = blockIdx.x / (ZDIM/64);
    const int bn = blockIdx.x % (ZDIM/64);
    const int tid  = threadIdx.x;
    const int lane = tid & 63;
    const int w    = tid >> 6;
    const int wm = w >> 1, wn = w & 1;
    const int q   = lane >> 4;
    const int l15 = lane & 15;

    f32x4 acc[2][2] = {};

    const int sm = tid & 63;
    const int sk = (tid >> 6) * 8;
    const int gr = t0*32 + bm*64 + sm;
    const float*  Arow  = nullptr;
    const bf16_t* Ahrow = nullptr;
    const bf16_t* Alrow = nullptr;
    if constexpr (MODE == 0) {
        int tt = gr >> 5, bb = gr & 31;
        Arow = Afp + ((size_t)bb * T_STEPS + tt) * 256;
    } else {
        Ahrow = Ahi + (size_t)gr * HDIM;
        Alrow = Alo + (size_t)gr * HDIM;
    }
    const int gcol = bn*64 + sm;

    for (int k0 = 0; k0 < KTOT; k0 += 32) {
        if constexpr (MODE == 0) {
            f32x4 a0 = *(const f32x4*)(Arow + k0 + sk);
            f32x4 a1 = *(const f32x4*)(Arow + k0 + sk + 4);
            #pragma unroll
            for (int j = 0; j < 4; ++j) {
                split_bf16(a0[j], Ash[sm][sk+j],   Asl[sm][sk+j]);
                split_bf16(a1[j], Ash[sm][sk+4+j], Asl[sm][sk+4+j]);
            }
        } else {
            *(bf16x8*)&Ash[sm][sk] = *(const bf16x8*)(Ahrow + k0 + sk);
            *(bf16x8*)&Asl[sm][sk] = *(const bf16x8*)(Alrow + k0 + sk);
        }
        #pragma unroll
        for (int j = 0; j < 8; ++j) {
            float wv = W[(size_t)(k0 + sk + j) * ZDIM + gcol];
            split_bf16(wv, Bsh[sm][sk+j], Bsl[sm][sk+j]);
        }
        __syncthreads();
        #pragma unroll
        for (int mt = 0; mt < 2; ++mt) {
            #pragma unroll
            for (int nt = 0; nt < 2; ++nt) {
                bf16x8 ah = *(const bf16x8*)&Ash[wm*32 + mt*16 + l15][q*8];
                bf16x8 al = *(const bf16x8*)&Asl[wm*32 + mt*16 + l15][q*8];
                bf16x8 bh = *(const bf16x8*)&Bsh[wn*32 + nt*16 + l15][q*8];
                bf16x8 bl = *(const bf16x8*)&Bsl[wn*32 + nt*16 + l15][q*8];
                acc[mt][nt] = __builtin_amdgcn_mfma_f32_16x16x32_bf16(ah, bh, acc[mt][nt], 0, 0, 0);
                acc[mt][nt] = __builtin_amdgcn_mfma_f32_16x16x32_bf16(al, bh, acc[mt][nt], 0, 0, 0);
                acc[mt][nt] = __builtin_amdgcn_mfma_f32_16x16x32_bf16(ah, bl, acc[mt][nt], 0, 0, 0);
            }
        }
        __syncthreads();
    }
    #pragma unroll
    for (int mt = 0; mt < 2; ++mt) {
        int row = bm*64 + wm*32 + mt*16 + q*4;
        #pragma unroll
        for (int nt = 0; nt < 2; ++nt) {
            int col = bn*64 + wn*32 + nt*16 + l15;
            float bia = bias[col];
            #pragma unroll
            for (int r = 0; r < 4; ++r)
                xp[(size_t)(row + r)*ZDIM + col] = acc[mt][nt][r] + bia;
        }
    }
}

// ---------------- persistent recurrent scan: owner-LN, packed-h broadcast ----------
// grid 256 x 256. group gid=blk>>6 owns batches 8*gid..+7; block lid=blk&63 owns
// h-cols H0=lid*16..+15. W in register hi/lo bf16 A-fragments.
// Per step: MFMA -> gates -> [xp prefetch t+1] -> stats rendezvous (64B partials,
// butterfly) -> OWNER lanes compute LN+h (128 tanh/block, not 8192) and publish h
// as packed u32 (bf16hi<<16|lo) -> h rendezvous -> consumers unpack 32KB -> LDS.
// R5 was tanh-storm + gl/bl LDS-conflict + 16MB/step broadcast bound.
__global__ __launch_bounds__(256, 1) void scan_kernel(
    const float* __restrict__ Wh,      // [1024][4096] fp32 recurrent rows
    const float* __restrict__ xp,      // [cT*32][4096] fp32 x-proj (incl bias)
    const float* __restrict__ gamma,
    const float* __restrict__ beta,
    unsigned*    hpub,                 // [2][32][1024] packed h (coherent)
    float*       part,                 // [2][4][64][16] fp32 (coherent)
    unsigned*    sflag,                // [T][4][64] (zeroed)
    unsigned*    hflag,                // [T][4][64] (zeroed)
    bf16_t*      __restrict__ hseq_hi, // [T*32][1024] or null (layer0)
    bf16_t*      __restrict__ hseq_lo,
    float*       __restrict__ outlast, // [32][1024] or null (layer1)
    bf16_t*      __restrict__ hst_hi,  // [32][1024] chunk-carry
    bf16_t*      __restrict__ hst_lo,
    float*       __restrict__ cstate,  // [32][1024]
    float*       __restrict__ mustate, // [32]
    int t0, int t1)
{
    extern __shared__ char smem[];
    bf16_t* slab_hi = (bf16_t*)smem;                       // W staging
    bf16_t* slab_lo = (bf16_t*)(smem + 64*SLAB_STRIDE*2);
    bf16_t* hl_hi   = (bf16_t*)smem;                       // [8][1040] post-staging
    bf16_t* hl_lo   = (bf16_t*)(smem + 8*HL_STRIDE*2);
    float*  sred    = (float*)(smem + 16*HL_STRIDE*2);     // [4][16][2]
    float*  stot    = sred + 128;                          // [16]

    const int gid = blockIdx.x >> 6;
    const int lid = blockIdx.x & 63;
    const int B0  = gid * 8;
    const int H0  = lid * 16;
    const int tid  = threadIdx.x;
    const int lane = tid & 63;
    const int w    = tid >> 6;
    const int q    = lane >> 4;
    const int l15  = lane & 15;

    // ---- stage recurrent W slice -> registers (hi/lo A-fragments) via LDS slabs
    bf16x8 wf_hi[32], wf_lo[32];
    {
        const int kw   = tid >> 6;
        const int strip= (tid >> 4) & 3;
        const int col  = tid & 15;
        const int gc2  = strip*1024 + H0 + col;
        const int rr_w = col*4 + strip;
        #pragma unroll
        for (int s = 0; s < 4; ++s) {
            for (int j = 0; j < 64; ++j) {
                int kk = j*4 + kw;
                float v = Wh[(size_t)(s*256 + kk)*ZDIM + gc2];
                bf16_t hi, lo; split_bf16(v, hi, lo);
                slab_hi[rr_w*SLAB_STRIDE + kk] = hi;
                slab_lo[rr_w*SLAB_STRIDE + kk] = lo;
            }
            __syncthreads();
            #pragma unroll
            for (int kbl = 0; kbl < 8; ++kbl) {
                wf_hi[s*8+kbl] = *(const bf16x8*)&slab_hi[(16*w + l15)*SLAB_STRIDE + kbl*32 + q*8];
                wf_lo[s*8+kbl] = *(const bf16x8*)&slab_lo[(16*w + l15)*SLAB_STRIDE + kbl*32 + q*8];
            }
            __syncthreads();
        }
    }

    const int  bidx  = l15;
    const bool valid = bidx < 8;
    const int  batch = B0 + bidx;
    const int  hcl   = 4*w + q;
    const int  hcg   = H0 + hcl;
    const float g_r = gamma[hcg];
    const float b_r = beta[hcg];
    const size_t xpbase = (size_t)batch * ZDIM + (size_t)H0 + hcl;
    const int hrow  = (l15 < 8) ? l15 : 7;
    const int srow  = tid >> 5;     // staging row 0..7
    const int sli   = tid & 31;
    const int sbatch= B0 + srow;

    float c = 0.f, mu_prev = 0.f;
    if (t0 > 0) {
        if (valid) {
            c = cstate[(size_t)batch*HDIM + hcg];
            mu_prev = mustate[batch];
        }
        // prologue: stage h(t0-1) from chunk-carry
        #pragma unroll
        for (int j = 0; j < 8; ++j) {
            int d0 = (sli + j*32)*4;
            *(bf16x4*)&hl_hi[srow*HL_STRIDE + d0] = *(const bf16x4*)&hst_hi[(size_t)sbatch*HDIM + d0];
            *(bf16x4*)&hl_lo[srow*HL_STRIDE + d0] = *(const bf16x4*)&hst_lo[(size_t)sbatch*HDIM + d0];
        }
    }
    __syncthreads();

    // preload xp for first step
    float xpv[4] = {0.f, 0.f, 0.f, 0.f};
    if (valid) {
        const float* xpt = xp + (size_t)(t0 - t0) * (BATCH*ZDIM) + xpbase;
        #pragma unroll
        for (int r = 0; r < 4; ++r) xpv[r] = xpt[(size_t)r * 1024];
    }

    #pragma unroll 1
    for (int t = t0; t < t1; ++t) {
        f32x4 acc_hh = {0.f,0.f,0.f,0.f}, acc_lh = acc_hh, acc_hl = acc_hh;
        if (t > 0) {
            const bf16_t* Bh = hl_hi + (size_t)hrow * HL_STRIDE + q*8;
            const bf16_t* Bl = hl_lo + (size_t)hrow * HL_STRIDE + q*8;
            #pragma unroll
            for (int kb = 0; kb < 32; ++kb) {
                bf16x8 bh = *(const bf16x8*)(Bh + kb*32);
                bf16x8 bv = *(const bf16x8*)(Bl + kb*32);
                acc_hh = __builtin_amdgcn_mfma_f32_16x16x32_bf16(wf_hi[kb], bh, acc_hh, 0, 0, 0);
                acc_lh = __builtin_amdgcn_mfma_f32_16x16x32_bf16(wf_lo[kb], bh, acc_lh, 0, 0, 0);
                acc_hl = __builtin_amdgcn_mfma_f32_16x16x32_bf16(wf_hi[kb], bv, acc_hl, 0, 0, 0);
            }
        }
        float z[4];
        #pragma unroll
        for (int r = 0; r < 4; ++r)
            z[r] = ((acc_lh[r] + acc_hl[r]) + acc_hh[r]) + xpv[r];
        float zi = fminf(fmaxf(z[0], -6.f), 3.f);
        float zf = fminf(fmaxf(z[1], -6.f), 3.f);
        float ig = __expf(zi);
        float fg = __expf(zf);
        float cand = tanhf(z[2]);
        float sg = 1.f / (1.f + __expf(-z[3]));
        c = fg * c + ig * cand;

        // prefetch next step's xp NOW — a full step (~10 us) to complete off-chain
        if (valid && t+1 < t1) {
            const float* xpt = xp + (size_t)(t+1 - t0) * (BATCH*ZDIM) + xpbase;
            #pragma unroll
            for (int r = 0; r < 4; ++r) xpv[r] = xpt[(size_t)r * 1024];
        }

        const int par = t & 1;
        // ---- rendezvous 1: LN stats (64 B partials per block)
        float dm = valid ? (c - mu_prev) : 0.f;
        float s1 = dm, s2 = dm * dm;
        s1 += __shfl_xor(s1, 16); s2 += __shfl_xor(s2, 16);
        s1 += __shfl_xor(s1, 32); s2 += __shfl_xor(s2, 32);
        if (q == 0 && l15 < 8) { sred[(w*16 + l15)*2] = s1; sred[(w*16 + l15)*2 + 1] = s2; }
        __syncthreads();   // B1

        unsigned* sf = sflag + ((size_t)t*4 + gid)*64;
        if (w == 0) {
            if (lane < 16) {
                int b = lane >> 1, comp = lane & 1;
                float P = sred[(0*16+b)*2+comp] + sred[(1*16+b)*2+comp]
                        + sred[(2*16+b)*2+comp] + sred[(3*16+b)*2+comp];
                *(volatile float*)(part + (((size_t)par*4 + gid)*64 + lid)*16 + lane) = P;
            }
            asm volatile("s_waitcnt vmcnt(0)" ::: "memory");
            if (lane == 0)
                __hip_atomic_store(&sf[lid], 1u, __ATOMIC_RELAXED, __HIP_MEMORY_SCOPE_AGENT);
            for (;;) {
                unsigned f = __hip_atomic_load(&sf[lane], __ATOMIC_RELAXED, __HIP_MEMORY_SCOPE_AGENT);
                if (__ballot(f != 0u) == ~0ull) break;
                __builtin_amdgcn_s_sleep(1);
            }
            volatile const f32x4* pb = (volatile const f32x4*)(part + (((size_t)par*4 + gid)*64 + lane)*16);
            f32x4 p0 = pb[0], p1 = pb[1], p2 = pb[2], p3 = pb[3];
            #pragma unroll
            for (int m = 1; m < 64; m <<= 1) {
                #pragma unroll
                for (int e = 0; e < 4; ++e) {
                    p0[e] += __shfl_xor(p0[e], m);
                    p1[e] += __shfl_xor(p1[e], m);
                    p2[e] += __shfl_xor(p2[e], m);
                    p3[e] += __shfl_xor(p3[e], m);
                }
            }
            if (lane == 0) {
                *(f32x4*)&stot[0]  = p0;
                *(f32x4*)&stot[4]  = p1;
                *(f32x4*)&stot[8]  = p2;
                *(f32x4*)&stot[12] = p3;
            }
        }
        __syncthreads();   // B2: stot ready

        // ---- owner LN + h publish (only 128 tanh per block)
        if (valid) {
            float S1 = stot[2*bidx], S2 = stot[2*bidx + 1];
            float dmu = S1 * (1.f/1024.f);
            float mu  = mu_prev + dmu;
            float var = S2 * (1.f/1024.f) - dmu*dmu;
            float ln  = (c - mu) * rsqrtf(var + 1e-5f) * g_r + b_r;
            float hv  = sg * tanhf(ln);
            mu_prev = mu;
            bf16_t hi, lo; split_bf16(hv, hi, lo);
            unsigned u = ((unsigned)bf16_bits(hi) << 16) | (unsigned)bf16_bits(lo);
            *(volatile unsigned*)(hpub + ((size_t)par*32 + batch)*HDIM + hcg) = u;
        }
        __syncthreads();   // B2b: drains all waves' vmcnt -> h stores complete

        // ---- rendezvous 2: h ready
        unsigned* hf = hflag + ((size_t)t*4 + gid)*64;
        if (tid == 0)
            __hip_atomic_store(&hf[lid], 1u, __ATOMIC_RELAXED, __HIP_MEMORY_SCOPE_AGENT);
        if (w == 0) {
            for (;;) {
                unsigned f = __hip_atomic_load(&hf[lane], __ATOMIC_RELAXED, __HIP_MEMORY_SCOPE_AGENT);
                if (__ballot(f != 0u) == ~0ull) break;
                __builtin_amdgcn_s_sleep(1);
            }
        }
        __syncthreads();   // B2c

        // ---- staging: read packed h (4 KB/row), unpack -> LDS hi/lo
        volatile const u32x4* hrowp = (volatile const u32x4*)(hpub + ((size_t)par*32 + sbatch)*HDIM);
        const bool wr_seq = (hseq_hi != nullptr) && (lid == srow);
        const bool wr_hst = (t == t1-1) && (t1 < T_STEPS) && (lid == srow);
        const bool wr_out = (outlast != nullptr) && (t == T_STEPS-1) && (lid == srow);
        #pragma unroll 2
        for (int j = 0; j < 8; ++j) {
            int d0 = (sli + j*32)*4;
            u32x4 uv = hrowp[sli + j*32];
            bf16x4 bh, blv;
            #pragma unroll
            for (int e = 0; e < 4; ++e) {
                bh[e]  = bf16_from_bits((unsigned short)(uv[e] >> 16));
                blv[e] = bf16_from_bits((unsigned short)(uv[e] & 0xffffu));
            }
            *(bf16x4*)&hl_hi[srow*HL_STRIDE + d0] = bh;
            *(bf16x4*)&hl_lo[srow*HL_STRIDE + d0] = blv;
            if (wr_seq) {
                *(bf16x4*)&hseq_hi[((size_t)t*32 + sbatch)*HDIM + d0] = bh;
                *(bf16x4*)&hseq_lo[((size_t)t*32 + sbatch)*HDIM + d0] = blv;
            }
            if (wr_hst) {
                *(bf16x4*)&hst_hi[(size_t)sbatch*HDIM + d0] = bh;
                *(bf16x4*)&hst_lo[(size_t)sbatch*HDIM + d0] = blv;
            }
            if (wr_out) {
                f32x4 hv4;
                #pragma unroll
                for (int e = 0; e < 4; ++e) hv4[e] = (float)bh[e] + (float)blv[e];
                *(f32x4*)&outlast[(size_t)sbatch*HDIM + d0] = hv4;
            }
        }
        __syncthreads();   // B3: hl ready for next step's MFMA
    }

    // chunk-carry state
    if (t1 < T_STEPS) {
        if (valid) cstate[(size_t)batch*HDIM + hcg] = c;
        if (lid == 0 && w == 0 && q == 0 && l15 < 8) mustate[B0 + l15] = mu_prev;
    }
}

extern "C" void kernel_launch(void* const* d_in, const int* in_sizes, int n_in,
                              void* d_out, int out_size, void* d_ws, size_t ws_size,
                              hipStream_t stream) {
    (void)in_sizes; (void)n_in;
    const float* series = (const float*)d_in[0];
    const float* W0  = (const float*)d_in[1];
    const float* b0  = (const float*)d_in[2];
    const float* g0  = (const float*)d_in[3];
    const float* be0 = (const float*)d_in[4];
    const float* W1  = (const float*)d_in[5];
    const float* b1  = (const float*)d_in[6];
    const float* g1  = (const float*)d_in[7];
    const float* be1 = (const float*)d_in[8];
    float* out = (float*)d_out;
    unsigned char* ws = (unsigned char*)d_ws;

    int cT = 0;
    const int cands[4] = {256, 128, 64, 32};
    for (int i = 0; i < 4; ++i) {
        size_t need = (size_t)cands[i]*32*ZDIM*4 + 2*SZ_HSEQ + SZ_TAIL;
        if (need <= ws_size) { cT = cands[i]; break; }
    }
    if (cT == 0) {
        (void)hipMemsetAsync(d_out, 0, (size_t)out_size * sizeof(float), stream);
        return;
    }
    const size_t sz_xp = (size_t)cT*32*ZDIM*4;
    unsigned char* p = ws;
    float*    xp      = (float*)p;    p += sz_xp;
    bf16_t*   hseq_hi = (bf16_t*)p;   p += SZ_HSEQ;
    bf16_t*   hseq_lo = (bf16_t*)p;   p += SZ_HSEQ;
    unsigned* hpub    = (unsigned*)p; p += SZ_HPUB;
    float*    part    = (float*)p;    p += SZ_PART;
    unsigned* sflag0  = (unsigned*)p; p += SZ_FLAG;   // 4 contiguous flag arrays, zeroed
    unsigned* hflag0  = (unsigned*)p; p += SZ_FLAG;
    unsigned* sflag1  = (unsigned*)p; p += SZ_FLAG;
    unsigned* hflag1  = (unsigned*)p; p += SZ_FLAG;
    bf16_t*   hst_hi  = (bf16_t*)p;   p += SZ_HST;
    bf16_t*   hst_lo  = (bf16_t*)p;   p += SZ_HST;
    float*    cstate  = (float*)p;    p += SZ_CST;
    float*    mustate = (float*)p;

    (void)hipFuncSetAttribute((const void*)scan_kernel,
                              hipFuncAttributeMaxDynamicSharedMemorySize, SCAN_LDS);

    init_zero<<<(ZERO_WORDS + 255)/256, 256, 0, stream>>>(sflag0, ZERO_WORDS);

    const int nch = T_STEPS / cT;
    const int gemm_grid = (cT*32/64) * (ZDIM/64);

    // ---- layer 0 ----
    for (int ci = 0; ci < nch; ++ci) {
        int t0 = ci*cT, t1 = t0 + cT;
        gemm_xp<256, 0><<<gemm_grid, 256, 0, stream>>>(
            series, nullptr, nullptr, W0, b0, xp, t0);
        scan_kernel<<<256, 256, SCAN_LDS, stream>>>(
            W0 + (size_t)256*ZDIM, xp, g0, be0, hpub, part, sflag0, hflag0,
            hseq_hi, hseq_lo, nullptr, hst_hi, hst_lo, cstate, mustate, t0, t1);
    }
    // ---- layer 1 ----
    for (int ci = 0; ci < nch; ++ci) {
        int t0 = ci*cT, t1 = t0 + cT;
        gemm_xp<1024, 1><<<gemm_grid, 256, 0, stream>>>(
            nullptr, hseq_hi, hseq_lo, W1, b1, xp, t0);
        scan_kernel<<<256, 256, SCAN_LDS, stream>>>(
            W1 + (size_t)1024*ZDIM, xp, g1, be1, hpub, part, sflag1, hflag1,
            nullptr, nullptr, out, hst_hi, hst_lo, cstate, mustate, t0, t1);
    }
}